// Round 5
// baseline (352.356 us; speedup 1.0000x reference)
//
#include <hip/hip_runtime.h>
#include <math.h>

#define K 8
#define D 256
#define R 64
#define BT 256
#define GRIDMAX 4096
#define NSLOT 32
#define F_EPS 1e-12f
#define MOM 0.9f

typedef __attribute__((ext_vector_type(8))) short short8;
typedef __attribute__((ext_vector_type(4))) float f32x4;

#define WROW 528                    // bytes per LDS tile row (264 bf16, pad -> conflict-free)
#define WTILE (16 * WROW)           // per-wave private tile region: 8448 B
#define SCNT_OFF (4 * WTILE)        // 33792
#define ARENA_BYTES (SCNT_OFF + 32)

__device__ __forceinline__ unsigned int pack_bf2(float a, float b) {
    unsigned int ua = __float_as_uint(a), ub = __float_as_uint(b);
    ua = (ua + 0x7fffu + ((ua >> 16) & 1u)) >> 16;          // RNE, low half
    ub = (ub + 0x7fffu + ((ub >> 16) & 1u)) & 0xffff0000u;  // RNE, high half
    return ua | ub;
}
__device__ __forceinline__ float bf_lo(unsigned int d) { return __uint_as_float(d << 16); }
__device__ __forceinline__ float bf_hi(unsigned int d) { return __uint_as_float(d & 0xffff0000u); }

__device__ __forceinline__ float wave_allreduce_add(float v) {
#pragma unroll
    for (int m = 1; m < 64; m <<= 1) v += __shfl_xor(v, m, 64);
    return v;
}
__device__ __forceinline__ float readlane_f(float v, int l) {
    return __int_as_float(__builtin_amdgcn_readlane(__float_as_int(v), l));
}

// Load proto B-fragments for mfma_f32_16x16x32_bf16.
// B[k_local = (lane>>4)*8 + j][n = lane&15] ; B[k][n] = P[n][k_global]
__device__ __forceinline__ void load_bfrags(const float* __restrict__ P, int mrow, int sl,
                                            short8* bfrag) {
    const bool pv = mrow < K;
    const float* pb = P + mrow * D + sl * 8;
#pragma unroll
    for (int c = 0; c < 8; ++c) {
        float4 a = make_float4(0.f, 0.f, 0.f, 0.f), b = a;
        if (pv) {
            a = *(const float4*)(pb + c * 32);
            b = *(const float4*)(pb + c * 32 + 4);
        }
        union { unsigned int u[4]; short8 s; } f;
        f.u[0] = pack_bf2(a.x, a.y); f.u[1] = pack_bf2(a.z, a.w);
        f.u[2] = pack_bf2(b.x, b.y); f.u[3] = pack_bf2(b.z, b.w);
        bfrag[c] = f.s;
    }
}

// ---------------- Pass 1: source features -> cluster sums/counts ----------------
__global__ __launch_bounds__(BT) void k_source(const float* __restrict__ src,
                                               const float* __restrict__ P,
                                               float* __restrict__ ws_sums,   // [NSLOT][K*D]
                                               float* __restrict__ ws_cnts,   // [NSLOT][K]
                                               int nrows) {
    __shared__ __align__(16) unsigned char arena[ARENA_BYTES];
    float* scnt = (float*)(arena + SCNT_OFF);

    const int t = threadIdx.x;
    const int lane = t & 63;
    const int w = t >> 6;
    const int mrow = lane & 15;     // row within this wave's 16-row strip
    const int sl = lane >> 4;       // k-slice quarter
    unsigned char* mytile = arena + w * WTILE;

    if (t < K) scnt[t] = 0.0f;

    short8 bfrag[8];
    load_bfrags(P, mrow, sl, bfrag);

    float acc[K][4];
    float cnta[K];
#pragma unroll
    for (int k = 0; k < K; ++k) {
        cnta[k] = 0.0f;
#pragma unroll
        for (int j = 0; j < 4; ++j) acc[k][j] = 0.0f;
    }

    const int nTiles = (nrows + R - 1) / R;
    for (int tb = blockIdx.x; tb < nTiles; tb += gridDim.x) {
        const int rbase = tb * R + w * 16;
        const int grow = rbase + mrow;
        const bool valid = grow < nrows;
        const float* rp = src + (size_t)grow * D + sl * 8;

        f32x4 dacc = {0.f, 0.f, 0.f, 0.f};
        float nrm = 0.0f;
#pragma unroll
        for (int c = 0; c < 8; ++c) {
            float4 a = make_float4(0.f, 0.f, 0.f, 0.f), b = a;
            if (valid) {
                a = *(const float4*)(rp + c * 32);
                b = *(const float4*)(rp + c * 32 + 4);
            }
            nrm += a.x * a.x + a.y * a.y + a.z * a.z + a.w * a.w
                 + b.x * b.x + b.y * b.y + b.z * b.z + b.w * b.w;
            union { unsigned int u[4]; short8 s; uint4 q; } f;
            f.u[0] = pack_bf2(a.x, a.y); f.u[1] = pack_bf2(a.z, a.w);
            f.u[2] = pack_bf2(b.x, b.y); f.u[3] = pack_bf2(b.z, b.w);
            *(uint4*)(mytile + mrow * WROW + c * 64 + sl * 16) = f.q;   // A-layout row store
            dacc = __builtin_amdgcn_mfma_f32_16x16x32_bf16(f.s, bfrag[c], dacc, 0, 0, 0);
        }
        nrm += __shfl_xor(nrm, 16, 64);
        nrm += __shfl_xor(nrm, 32, 64);
        const float inv = 1.0f / fmaxf(sqrtf(nrm), F_EPS);

        // argmax over protos: dots at D[row=(lane>>4)*4+reg][proto=lane&15]
        float bv[4]; int bi[4];
#pragma unroll
        for (int j = 0; j < 4; ++j) { bv[j] = (mrow < K) ? dacc[j] : -1e30f; bi[j] = mrow; }
#pragma unroll
        for (int m = 1; m <= 4; m <<= 1) {
#pragma unroll
            for (int j = 0; j < 4; ++j) {
                float ov = __shfl_xor(bv[j], m, 64);
                int oi = __shfl_xor(bi[j], m, 64);
                if (ov > bv[j] || (ov == bv[j] && oi < bi[j])) { bv[j] = ov; bi[j] = oi; }
            }
        }

        // scatter this wave's 16 rows (reads the LDS it just wrote; same-wave, no barrier)
#pragma unroll
        for (int j = 0; j < 16; ++j) {
            if (rbase + j >= nrows) break;                         // uniform
            const int a = __builtin_amdgcn_readlane(bi[j & 3], (j >> 2) * 16);
            const float iv = readlane_f(inv, j);
            uint2 dv = *(const uint2*)(mytile + j * WROW + lane * 8);
            float x0 = bf_lo(dv.x) * iv, x1 = bf_hi(dv.x) * iv;
            float x2 = bf_lo(dv.y) * iv, x3 = bf_hi(dv.y) * iv;
            switch (a) {
#define SC_CASE(KK) case KK: acc[KK][0] += x0; acc[KK][1] += x1; acc[KK][2] += x2; acc[KK][3] += x3; cnta[KK] += 1.0f; break;
                SC_CASE(0) SC_CASE(1) SC_CASE(2) SC_CASE(3)
                SC_CASE(4) SC_CASE(5) SC_CASE(6) SC_CASE(7)
#undef SC_CASE
            }
        }
    }

    // ---- Flush: combine 4 waves in LDS (overlay tile), then global atomics ----
    __syncthreads();
    float* combine = (float*)arena;   // 32 KB overlay
#pragma unroll
    for (int k = 0; k < K; ++k)
        *(float4*)(combine + w * 2048 + k * 256 + lane * 4) =
            make_float4(acc[k][0], acc[k][1], acc[k][2], acc[k][3]);
    if (lane == 0) {
#pragma unroll
        for (int k = 0; k < K; ++k) atomicAdd(&scnt[k], cnta[k]);
    }
    __syncthreads();
    const int slot = blockIdx.x & (NSLOT - 1);
    float* gs = ws_sums + (size_t)slot * (K * D);
    for (int i = t; i < K * D; i += BT) {
        float s = combine[i] + combine[2048 + i] + combine[4096 + i] + combine[6144 + i];
        unsafeAtomicAdd(&gs[i], s);
    }
    if (t < K) unsafeAtomicAdd(&ws_cnts[slot * K + t], scnt[t]);
}

// ---------------- Prototype momentum update + renormalize (1 block, wave per proto) ----------------
__global__ __launch_bounds__(512) void k_protos(const float* __restrict__ sums_slots,
                                                const float* __restrict__ cnt_slots,
                                                const float* __restrict__ protos_in,
                                                float* __restrict__ protos_out) {
    const int t = threadIdx.x;
    const int k = t >> 6;
    const int lane = t & 63;

    float c = 0.0f;
    for (int s = 0; s < NSLOT; ++s) c += cnt_slots[s * K + k];

    float4 sm = make_float4(0.f, 0.f, 0.f, 0.f);
    for (int s = 0; s < NSLOT; ++s) {
        float4 v = *(const float4*)(sums_slots + (size_t)s * (K * D) + k * D + lane * 4);
        sm.x += v.x; sm.y += v.y; sm.z += v.z; sm.w += v.w;
    }
    const float cc = fmaxf(c, 1.0f);
    float4 m = make_float4(sm.x / cc, sm.y / cc, sm.z / cc, sm.w / cc);
    float nr = wave_allreduce_add(m.x * m.x + m.y * m.y + m.z * m.z + m.w * m.w);
    const float s1 = 1.0f / fmaxf(sqrtf(nr), F_EPS);
    float4 pin = *(const float4*)(protos_in + k * D + lane * 4);
    float4 upd;
    if (c > 0.0f) {
        upd = make_float4(MOM * pin.x + (1.0f - MOM) * m.x * s1,
                          MOM * pin.y + (1.0f - MOM) * m.y * s1,
                          MOM * pin.z + (1.0f - MOM) * m.z * s1,
                          MOM * pin.w + (1.0f - MOM) * m.w * s1);
    } else {
        upd = pin;
    }
    float n2 = wave_allreduce_add(upd.x * upd.x + upd.y * upd.y + upd.z * upd.z + upd.w * upd.w);
    const float s2 = 1.0f / fmaxf(sqrtf(n2), F_EPS);
    *(float4*)(protos_out + k * D + lane * 4) =
        make_float4(upd.x * s2, upd.y * s2, upd.z * s2, upd.w * s2);
}

// ---------------- Pass 2: target features -> mean(1 - max cos) ----------------
__global__ __launch_bounds__(BT) void k_target(const float* __restrict__ tgt,
                                               const float* __restrict__ P,
                                               float* __restrict__ loss_slots,
                                               int nrows) {
    const int t = threadIdx.x;
    const int lane = t & 63;
    const int w = t >> 6;
    const int mrow = lane & 15;
    const int sl = lane >> 4;

    short8 bfrag[8];
    load_bfrags(P, mrow, sl, bfrag);

    float lacc = 0.0f;

    const int nTiles = (nrows + R - 1) / R;
    for (int tb = blockIdx.x; tb < nTiles; tb += gridDim.x) {
        const int rbase = tb * R + w * 16;
        const int grow = rbase + mrow;
        const bool valid = grow < nrows;
        const float* rp = tgt + (size_t)grow * D + sl * 8;

        f32x4 dacc = {0.f, 0.f, 0.f, 0.f};
        float nrm = 0.0f;
#pragma unroll
        for (int c = 0; c < 8; ++c) {
            float4 a = make_float4(0.f, 0.f, 0.f, 0.f), b = a;
            if (valid) {
                a = *(const float4*)(rp + c * 32);
                b = *(const float4*)(rp + c * 32 + 4);
            }
            nrm += a.x * a.x + a.y * a.y + a.z * a.z + a.w * a.w
                 + b.x * b.x + b.y * b.y + b.z * b.z + b.w * b.w;
            union { unsigned int u[4]; short8 s; } f;
            f.u[0] = pack_bf2(a.x, a.y); f.u[1] = pack_bf2(a.z, a.w);
            f.u[2] = pack_bf2(b.x, b.y); f.u[3] = pack_bf2(b.z, b.w);
            dacc = __builtin_amdgcn_mfma_f32_16x16x32_bf16(f.s, bfrag[c], dacc, 0, 0, 0);
        }
        nrm += __shfl_xor(nrm, 16, 64);
        nrm += __shfl_xor(nrm, 32, 64);
        const float inv = 1.0f / fmaxf(sqrtf(nrm), F_EPS);

        float mx[4];
#pragma unroll
        for (int j = 0; j < 4; ++j) mx[j] = (mrow < K) ? dacc[j] : -1e30f;
#pragma unroll
        for (int m = 1; m <= 4; m <<= 1) {
#pragma unroll
            for (int j = 0; j < 4; ++j) mx[j] = fmaxf(mx[j], __shfl_xor(mx[j], m, 64));
        }

#pragma unroll
        for (int j = 0; j < 16; ++j) {
            if (rbase + j >= nrows) break;                         // uniform
            const float bd = readlane_f(mx[j & 3], (j >> 2) * 16);
            const float iv = readlane_f(inv, j);
            lacc += 1.0f - bd * iv;                                // wave-uniform
        }
    }

    if (lane == 0)
        unsafeAtomicAdd(&loss_slots[blockIdx.x & (NSLOT - 1)], lacc);
}

__global__ void k_loss(const float* __restrict__ loss_slots, float* __restrict__ out, float invN) {
    float v = (threadIdx.x < NSLOT) ? loss_slots[threadIdx.x] : 0.0f;
    v = wave_allreduce_add(v);
    if (threadIdx.x == 0) out[0] = v * invN;
}

extern "C" void kernel_launch(void* const* d_in, const int* in_sizes, int n_in,
                              void* d_out, int out_size, void* d_ws, size_t ws_size,
                              hipStream_t stream) {
    const float* src = (const float*)d_in[0];
    const float* tgt = (const float*)d_in[1];
    const float* protos = (const float*)d_in[2];
    float* out = (float*)d_out;
    float* ws = (float*)d_ws;

    const int Ns = in_sizes[0] / D;
    const int Nt = in_sizes[1] / D;

    float* ws_sums = ws;                                 // NSLOT*K*D
    float* ws_cnts = ws_sums + NSLOT * K * D;            // NSLOT*K
    float* ws_loss = ws_cnts + NSLOT * K;                // NSLOT
    float* ws_protos = ws_loss + NSLOT;                  // K*D (no zero-init needed)
    const size_t zero_bytes = (size_t)(NSLOT * K * D + NSLOT * K + NSLOT) * sizeof(float);
    hipMemsetAsync(d_ws, 0, zero_bytes, stream);

    const int nTilesS = (Ns + R - 1) / R;
    const int nTilesT = (Nt + R - 1) / R;
    const int gridS = (nTilesS < GRIDMAX) ? nTilesS : GRIDMAX;
    const int gridT = (nTilesT < GRIDMAX) ? nTilesT : GRIDMAX;

    k_source<<<gridS, BT, 0, stream>>>(src, protos, ws_sums, ws_cnts, Ns);
    k_protos<<<1, 512, 0, stream>>>(ws_sums, ws_cnts, protos, ws_protos);
    k_target<<<gridT, BT, 0, stream>>>(tgt, ws_protos, ws_loss, Nt);
    k_loss<<<1, 64, 0, stream>>>(ws_loss, out, 1.0f / (float)Nt);
}